// Round 16
// baseline (514.721 us; speedup 1.0000x reference)
//
#include <hip/hip_runtime.h>

#define BB 16
#define TT 128
#define HH 34
#define WW 34
#define HWSZ (HH*WW)                 // 1156
#define NP1 (BB*TT*HH*WW)            // 2367488
#define TD 64
#define HD 17
#define WD 17
#define NP2 (BB*TD*HD*WD)            // 295936
#define NW1 (NP1/64)                 // 36992
#define NW2 (NP2/64)                 // 4624
#define CAP1 262144
#define CAP2 131072
#define G2 1024
#define G3 512

typedef __attribute__((ext_vector_type(8))) short bf16x8;
typedef __attribute__((ext_vector_type(4))) float f32x4;

__device__ inline unsigned short f2bf(float f) {
  unsigned u = __float_as_uint(f);
  unsigned r = (u + 0x7fff + ((u >> 16) & 1)) >> 16;
  return (unsigned short)r;
}
__device__ inline float bf2f(unsigned short s) {
  return __uint_as_float((unsigned)s << 16);
}

// ---------------- ballot1 ----------------
__global__ void k_ballot1(const float* __restrict__ x, unsigned long long* __restrict__ b1) {
  int i = blockIdx.x * 256 + threadIdx.x;
  int hw = i % HWSZ;
  int bt = i / HWSZ;
  const float* px = x + (size_t)bt * 2 * HWSZ + hw;
  bool act = (fabsf(px[0]) + fabsf(px[HWSZ])) > 0.0f;
  unsigned long long m = __ballot(act);
  if ((threadIdx.x & 63) == 0) b1[i >> 6] = m;
}

// ---------------- ballot2 ----------------
__global__ void k_ballot2(const unsigned long long* __restrict__ b1,
                          unsigned long long* __restrict__ b2) {
  int i = blockIdx.x * 256 + threadIdx.x;
  if (i >= NP2) return;
  int ow = i % WD; int r = i / WD;
  int oh = r % HD; r /= HD;
  int od = r % TD; int b = r / TD;
  bool act = false;
  for (int dt = 0; dt < 2; dt++)
    for (int dh = 0; dh < 2; dh++)
      for (int dw = 0; dw < 2; dw++) {
        int t = od * 2 + dt, h = oh * 2 + dh, w = ow * 2 + dw;
        int lin = ((b * TT + t) * HH + h) * WW + w;
        if ((b1[lin >> 6] >> (lin & 63)) & 1ull) act = true;
      }
  unsigned long long m = __ballot(act);
  if ((threadIdx.x & 63) == 0) b2[i >> 6] = m;
}

// ---------------- scan ----------------
__global__ __launch_bounds__(1024) void k_scan(
    const unsigned long long* __restrict__ b1, const unsigned long long* __restrict__ b2,
    int* __restrict__ wb1, int* __restrict__ wb2,
    int* __restrict__ counter1, int* __restrict__ counter2, float* __restrict__ cnt) {
  __shared__ int wsum[16];
  __shared__ int wpre[16];
  __shared__ int tots[2];
  int tid = threadIdx.x, lane = tid & 63, wv = tid >> 6;

  const int CH1 = (NW1 + 1023) / 1024;
  int lo = tid * CH1, hi = min(lo + CH1, NW1);
  int s = 0;
  for (int i = lo; i < hi; i++) s += __popcll(b1[i]);
  int sc = s;
  #pragma unroll
  for (int d = 1; d < 64; d <<= 1) { int y = __shfl_up(sc, d); if (lane >= d) sc += y; }
  if (lane == 63) wsum[wv] = sc;
  __syncthreads();
  if (wv == 0 && lane < 16) {
    int v = wsum[lane];
    int p = v;
    #pragma unroll
    for (int d = 1; d < 16; d <<= 1) { int y = __shfl_up(p, d); if (lane >= d) p += y; }
    wpre[lane] = p - v;
    if (lane == 15) tots[0] = p;
  }
  __syncthreads();
  {
    int base = wpre[wv] + (sc - s);
    for (int i = lo; i < hi; i++) { wb1[i] = base; base += __popcll(b1[i]); }
  }
  if (tid == 0) *counter1 = tots[0];
  __syncthreads();

  const int CH2 = (NW2 + 1023) / 1024;
  lo = tid * CH2; hi = min(lo + CH2, NW2);
  s = 0;
  for (int i = lo; i < hi; i++) s += __popcll(b2[i]);
  sc = s;
  #pragma unroll
  for (int d = 1; d < 64; d <<= 1) { int y = __shfl_up(sc, d); if (lane >= d) sc += y; }
  if (lane == 63) wsum[wv] = sc;
  __syncthreads();
  if (wv == 0 && lane < 16) {
    int v = wsum[lane];
    int p = v;
    #pragma unroll
    for (int d = 1; d < 16; d <<= 1) { int y = __shfl_up(p, d); if (lane >= d) p += y; }
    wpre[lane] = p - v;
    if (lane == 15) tots[1] = p;
  }
  __syncthreads();
  {
    int base = wpre[wv] + (sc - s);
    for (int i = lo; i < hi; i++) { wb2[i] = base; base += __popcll(b2[i]); }
  }
  if (tid == 0) *counter2 = tots[1];
  __syncthreads();
  if (tid < 16) {
    int c0 = wb2[tid * 289];
    int c1 = (tid == 15) ? tots[1] : wb2[(tid + 1) * 289];
    cnt[tid] = (float)(c1 - c0);
  }
}

// ---------------- fill1 ----------------
__global__ void k_fill1(const unsigned long long* __restrict__ b1,
                        const int* __restrict__ wb1, int* __restrict__ idx1) {
  int i = blockIdx.x * 256 + threadIdx.x;
  unsigned long long m = b1[i >> 6];
  int lane = i & 63;
  int p = -1;
  if ((m >> lane) & 1ull) {
    p = wb1[i >> 6] + __popcll(m & ((1ull << lane) - 1ull));
    if (p >= CAP1) p = -1;
  }
  idx1[i] = p;
}

// ---------------- fill2 ----------------
__global__ void k_fill2(const unsigned long long* __restrict__ b2,
                        const int* __restrict__ wb2,
                        int* __restrict__ idx2, int* __restrict__ list2) {
  int i = blockIdx.x * 256 + threadIdx.x;
  if (i >= NP2) return;
  unsigned long long m = b2[i >> 6];
  int lane = i & 63;
  int p = -1;
  if ((m >> lane) & 1ull) {
    p = wb2[i >> 6] + __popcll(m & ((1ull << lane) - 1ull));
    if (p < CAP2) list2[p] = i; else p = -1;
  }
  idx2[i] = p;
}

// ---------------- conv1: event-queue per position ----------------
__global__ __launch_bounds__(256) void k_conv1e(
    const float* __restrict__ x, const float* __restrict__ w1,
    const unsigned long long* __restrict__ b1, const int* __restrict__ wb1,
    unsigned short* __restrict__ h1c) {
  __shared__ unsigned short w1s[8000];
  __shared__ unsigned int plist[384];
  __shared__ unsigned long long q[4][128];
  __shared__ int pcnt;
  int tid = threadIdx.x;
  int b = blockIdx.x >> 7;
  int t0 = blockIdx.x & 127;
  if (tid == 0) pcnt = 0;
  for (int j = tid; j < 8000; j += 256) w1s[j] = f2bf(w1[j]);
  __syncthreads();
  int slabbase = (b * TT + t0) * HWSZ;
  for (int hw = tid; hw < HWSZ; hw += 256) {
    int lin = slabbase + hw;
    unsigned long long m = b1[lin >> 6];
    int ln = lin & 63;
    if ((m >> ln) & 1ull) {
      int p = wb1[lin >> 6] + __popcll(m & ((1ull << ln) - 1ull));
      if (p < CAP1) {
        int s = atomicAdd(&pcnt, 1);
        if (s < 384) plist[s] = ((unsigned)p << 11) | (unsigned)hw;
      }
    }
  }
  __syncthreads();
  int n = min(pcnt, 384);
  int lane = tid & 63, wid = tid >> 6;
  int oc = lane & 31, c = lane >> 5;
  int woff = (oc * 2 + c) * 125;
  int csh = c * 16;
  int kt = lane / 5, kh = lane - kt * 5;
  const float* xb = x + (size_t)b * TT * 2 * HWSZ;
  for (int li = wid; li < n; li += 4) {
    unsigned e = plist[li];
    int hw = e & 0x7ff;
    int p = e >> 11;
    int h_ = hw / 34, w_ = hw - h_ * 34;
    int cntA = 0;
    unsigned m5 = 0;
    int t2 = 0, h2 = 0;
    if (lane < 25) {
      t2 = t0 + kt - 2;
      h2 = h_ + kh - 2;
      if ((unsigned)t2 < TT && (unsigned)h2 < HH) {
        int kwmin = (w_ < 2) ? (2 - w_) : 0;
        int kwmax = (w_ > 31) ? (35 - w_) : 4;
        int lin = ((b * TT + t2) * HH + h2) * WW + (w_ + kwmin - 2);
        int wi = lin >> 6, sh = lin & 63;
        unsigned long long v = b1[wi] >> sh;
        if (sh > 59) v |= b1[wi + 1] << (64 - sh);
        m5 = ((unsigned)v & ((1u << (kwmax - kwmin + 1)) - 1u)) << kwmin;
        cntA = __popc(m5);
      }
    }
    int inc = cntA;
    #pragma unroll
    for (int d = 1; d < 64; d <<= 1) { int y = __shfl_up(inc, d); if (lane >= d) inc += y; }
    int off = inc - cntA;
    int ne = __shfl(inc, 63);
    unsigned mm = m5;
    while (mm) {
      int kw = __ffs(mm) - 1; mm &= mm - 1;
      int w2 = w_ + kw - 2;
      int xoff = (t2 * 2) * HWSZ + h2 * 34 + w2;
      unsigned short xv0 = f2bf(xb[xoff]);
      unsigned short xv1 = f2bf(xb[xoff + HWSZ]);
      int tap = (kt * 5 + kh) * 5 + kw;
      q[wid][off++] = (unsigned long long)((unsigned)xv0 | ((unsigned)xv1 << 16)) |
                      ((unsigned long long)tap << 32);
    }
    float acc = 0.f;
    for (int e2 = 0; e2 < ne; e2++) {
      unsigned long long ent = q[wid][e2];
      int tap = (int)(ent >> 32);
      float xv = bf2f((unsigned short)((ent >> csh) & 0xffffull));
      acc += xv * bf2f(w1s[woff + tap]);
    }
    float other = __shfl_down(acc, 32);
    if (lane < 32) h1c[(size_t)p * 32 + oc] = f2bf(acc + other);
  }
}

// ---------------- weight transposes to bf16 [tap][oc][c] ----------------
__global__ void k_tw2b(const float* __restrict__ w2, unsigned short* __restrict__ w2b) {
  int i = blockIdx.x * blockDim.x + threadIdx.x;
  if (i >= 125 * 64 * 32) return;
  int c = i & 31; int r = i >> 5;
  int oc = r & 63; int tap = r >> 6;
  w2b[i] = f2bf(w2[((size_t)oc * 32 + c) * 125 + tap]);
}
__global__ void k_tw3b(const float* __restrict__ w3, unsigned short* __restrict__ w3b) {
  int i = blockIdx.x * blockDim.x + threadIdx.x;
  if (i >= 27 * 128 * 64) return;
  int c = i & 63; int r = i >> 6;
  int oc = r & 127; int tap = r >> 7;
  w3b[i] = f2bf(w3[((size_t)oc * 64 + c) * 27 + tap]);
}

// ---------------- conv2 MFMA: M=128, FRAGMENT-DIRECT, barrier-free tap loop ----
#define M2 128
__global__ __launch_bounds__(256) void k_conv2m(
    const unsigned short* __restrict__ h1c,   // [CAP1][32] bf16
    const unsigned short* __restrict__ w2b,   // [125][64][32] bf16
    const int* __restrict__ idx1,
    const int* __restrict__ list2, const int* __restrict__ counter2,
    unsigned short* __restrict__ h2c) {       // [CAP2][64] bf16
  __shared__ int4 mc[M2];     // 2048 B
  __shared__ int klut[125];
  int tid = threadIdx.x;
  int lane = tid & 63, wid = tid >> 6;
  int fr = lane & 15, fq = lane >> 4;
  int wr = wid * 32;          // wave owns rows [wr, wr+32), all 64 cols
  if (tid < 125) {
    int kt = tid / 25, r2 = tid - kt * 25;
    klut[tid] = kt | ((r2 / 5) << 4) | ((r2 % 5) << 8);
  }
  int count2 = min(*counter2, CAP2);
  int nchunk = (count2 + M2 - 1) >> 7;
  // XCD swizzle (G2 % 8 == 0)
  int chid = (blockIdx.x & 7) * (G2 >> 3) + (blockIdx.x >> 3);
  const bf16x8 z = {0,0,0,0,0,0,0,0};
  __syncthreads();
  for (int ch = chid; ch < nchunk; ch += gridDim.x) {
    __syncthreads();
    if (tid < M2) {
      int p = ch * M2 + tid;
      int m = (p < count2) ? list2[p] : -1;
      int4 qq; qq.x = -1; qq.y = 0; qq.z = 0; qq.w = 0;
      if (m >= 0) {
        int ow = m % WD; int r = m / WD;
        int oh = r % HD; r /= HD;
        qq.x = r / TD; qq.y = r % TD; qq.z = oh; qq.w = ow;
      }
      mc[tid] = qq;
    }
    __syncthreads();
    // per-lane: two A-rows (positions wr+fr and wr+16+fr)
    int4 q0 = mc[wr + fr];
    int4 q1 = mc[wr + 16 + fr];
    int tb0 = q0.y * 2 - 2, hb0 = q0.z * 2 - 2, wb0 = q0.w * 2 - 2;
    int tb1 = q1.y * 2 - 2, hb1 = q1.z * 2 - 2, wb1v = q1.w * 2 - 2;
    bool ok0 = q0.x >= 0, ok1 = q1.x >= 0;
    auto rowfor0 = [&](int tap) -> int {
      int k = klut[tap];
      int t = tb0 + (k & 15), h = hb0 + ((k >> 4) & 15), w = wb0 + (k >> 8);
      int row = -1;
      if (ok0 && (unsigned)t < TT && (unsigned)h < HH && (unsigned)w < WW)
        row = idx1[((q0.x * TT + t) * HH + h) * WW + w];
      return row;
    };
    auto rowfor1 = [&](int tap) -> int {
      int k = klut[tap];
      int t = tb1 + (k & 15), h = hb1 + ((k >> 4) & 15), w = wb1v + (k >> 8);
      int row = -1;
      if (ok1 && (unsigned)t < TT && (unsigned)h < HH && (unsigned)w < WW)
        row = idx1[((q1.x * TT + t) * HH + h) * WW + w];
      return row;
    };
    f32x4 acc[2][4];
    #pragma unroll
    for (int i = 0; i < 2; i++)
      #pragma unroll
      for (int j = 0; j < 4; j++) acc[i][j] = (f32x4){0.f, 0.f, 0.f, 0.f};
    // register pipeline: rows 2 ahead, data 1 ahead; NO LDS, NO barriers
    const unsigned short* wB = w2b + (size_t)fr * 32 + fq * 8;  // + ni*512 + tap*2048
    int r0 = rowfor0(0), r1 = rowfor1(0);
    bf16x8 a0 = (r0 >= 0) ? *(const bf16x8*)(h1c + (size_t)r0 * 32 + fq * 8) : z;
    bf16x8 a1 = (r1 >= 0) ? *(const bf16x8*)(h1c + (size_t)r1 * 32 + fq * 8) : z;
    bf16x8 bfr[4];
    #pragma unroll
    for (int ni = 0; ni < 4; ni++) bfr[ni] = *(const bf16x8*)(wB + ni * 512);
    int rn0 = rowfor0(1), rn1 = rowfor1(1);
    for (int tap = 0; tap < 125; ++tap) {
      bool more = tap < 124;
      bf16x8 na0 = z, na1 = z, nb[4];
      int rw0 = -1, rw1 = -1;
      if (more) {
        if (rn0 >= 0) na0 = *(const bf16x8*)(h1c + (size_t)rn0 * 32 + fq * 8);
        if (rn1 >= 0) na1 = *(const bf16x8*)(h1c + (size_t)rn1 * 32 + fq * 8);
        const unsigned short* wt = wB + (size_t)(tap + 1) * 2048;
        #pragma unroll
        for (int ni = 0; ni < 4; ni++) nb[ni] = *(const bf16x8*)(wt + ni * 512);
        if (tap < 123) { rw0 = rowfor0(tap + 2); rw1 = rowfor1(tap + 2); }
      }
      #pragma unroll
      for (int ni = 0; ni < 4; ni++) {
        acc[0][ni] = __builtin_amdgcn_mfma_f32_16x16x32_bf16(a0, bfr[ni], acc[0][ni], 0, 0, 0);
        acc[1][ni] = __builtin_amdgcn_mfma_f32_16x16x32_bf16(a1, bfr[ni], acc[1][ni], 0, 0, 0);
      }
      if (more) {
        a0 = na0; a1 = na1;
        #pragma unroll
        for (int ni = 0; ni < 4; ni++) bfr[ni] = nb[ni];
        rn0 = rw0; rn1 = rw1;
      }
    }
    int base = ch * M2;
    #pragma unroll
    for (int mi = 0; mi < 2; mi++)
      #pragma unroll
      for (int ni = 0; ni < 4; ni++)
        #pragma unroll
        for (int j = 0; j < 4; j++) {
          int r = wr + mi * 16 + fq * 4 + j;
          int p = base + r;
          if (p < count2) {
            int col = ni * 16 + fr;
            h2c[(size_t)p * 64 + col] = f2bf(fmaxf(acc[mi][ni][j], 0.f));
          }
        }
  }
}

// ---------------- conv3 MFMA (R14): As+Bs dbuf, rowsL, S3=72, h3 pooling ----
#define S3 72
#define SH3 132
__global__ __launch_bounds__(256) void k_conv3m(
    const unsigned short* __restrict__ h2c,   // [CAP2][64] bf16
    const unsigned short* __restrict__ w3b,   // [27][128][64] bf16
    const int* __restrict__ idx2,
    const int* __restrict__ list2, const int* __restrict__ counter2,
    float* __restrict__ partial) {            // [G3][2048] fp32
  __shared__ __align__(16) unsigned short As[2][64 * S3];   // 18432 B
  __shared__ __align__(16) unsigned short Bs[2][128 * S3];  // 36864 B
  __shared__ float pools[2048];
  __shared__ int rowsL[27 * 64];
  __shared__ int4 mc[64];
  __shared__ int posb[64];
  int tid = threadIdx.x;
  int lane = tid & 63, wid = tid >> 6;
  int fr = lane & 15, fq = lane >> 4;
  int wr = (wid >> 1) * 32, wc = (wid & 1) * 64;
  for (int j = tid; j < 2048; j += 256) pools[j] = 0.f;
  int count2 = min(*counter2, CAP2);
  int nchunk = (count2 + 63) >> 6;
  int spos = tid >> 2, sq = tid & 3;
  int boc = tid >> 1, bh = tid & 1;
  // XCD swizzle (G3 % 8 == 0)
  int chid = (blockIdx.x & 7) * (G3 >> 3) + (blockIdx.x >> 3);
  for (int ch = chid; ch < nchunk; ch += gridDim.x) {
    __syncthreads();
    if (tid < 64) {
      int p = ch * 64 + tid;
      int m = (p < count2) ? list2[p] : -1;
      int4 q; q.x = -1; q.y = 0; q.z = 0; q.w = 0;
      if (m >= 0) {
        int ow = m % WD; int r = m / WD;
        int oh = r % HD; r /= HD;
        q.x = r / TD; q.y = r % TD; q.z = oh; q.w = ow;
      }
      mc[tid] = q;
      posb[tid] = (q.x >= 0) ? q.x : 0;
    }
    __syncthreads();
    for (int j = tid; j < 27 * 64; j += 256) {
      int tap = j >> 6, pos = j & 63;
      int4 q = mc[pos];
      int row = -1;
      if (q.x >= 0) {
        int dt = tap / 9 - 1, dh = (tap / 3) % 3 - 1, dw = tap % 3 - 1;
        int t = q.y + dt, h = q.z + dh, w = q.w + dw;
        if ((unsigned)t < TD && (unsigned)h < HD && (unsigned)w < WD)
          row = idx2[((q.x * TD + t) * HD + h) * WD + w];
      }
      rowsL[j] = row;
    }
    __syncthreads();
    f32x4 acc[2][4];
    #pragma unroll
    for (int i = 0; i < 2; i++)
      #pragma unroll
      for (int j = 0; j < 4; j++) acc[i][j] = (f32x4){0.f, 0.f, 0.f, 0.f};
    int4 rA0 = {0, 0, 0, 0}, rA1 = {0, 0, 0, 0};
    {
      int row = rowsL[spos];
      if (row >= 0) {
        const unsigned short* s = h2c + (size_t)row * 64 + sq * 16;
        rA0 = *(const int4*)s;
        rA1 = *(const int4*)(s + 8);
      }
    }
    int4 rB0, rB1, rB2, rB3;
    {
      const unsigned short* wsrc = w3b + (size_t)boc * 64 + bh * 32;
      rB0 = *(const int4*)(wsrc);
      rB1 = *(const int4*)(wsrc + 8);
      rB2 = *(const int4*)(wsrc + 16);
      rB3 = *(const int4*)(wsrc + 24);
    }
    for (int tap = 0; tap < 27; tap++) {
      int bsel = tap & 1;
      {
        unsigned short* ad = &As[bsel][spos * S3 + sq * 16];
        *(int4*)(ad) = rA0;
        *(int4*)(ad + 8) = rA1;
        unsigned short* bd = &Bs[bsel][boc * S3 + bh * 32];
        *(int4*)(bd) = rB0;
        *(int4*)(bd + 8) = rB1;
        *(int4*)(bd + 16) = rB2;
        *(int4*)(bd + 24) = rB3;
      }
      if (tap < 26) {
        int row = rowsL[(tap + 1) * 64 + spos];
        int4 v0 = {0, 0, 0, 0}, v1 = {0, 0, 0, 0};
        if (row >= 0) {
          const unsigned short* s = h2c + (size_t)row * 64 + sq * 16;
          v0 = *(const int4*)s;
          v1 = *(const int4*)(s + 8);
        }
        rA0 = v0; rA1 = v1;
        const unsigned short* wsrc = w3b + ((size_t)(tap + 1) * 128 + boc) * 64 + bh * 32;
        rB0 = *(const int4*)(wsrc);
        rB1 = *(const int4*)(wsrc + 8);
        rB2 = *(const int4*)(wsrc + 16);
        rB3 = *(const int4*)(wsrc + 24);
      }
      __syncthreads();
      const unsigned short* ap = &As[bsel][(wr + fr) * S3 + fq * 8];
      const unsigned short* bp = &Bs[bsel][(wc + fr) * S3 + fq * 8];
      #pragma unroll
      for (int kk = 0; kk < 2; kk++) {
        bf16x8 a0 = *(const bf16x8*)(ap + kk * 32);
        bf16x8 a1 = *(const bf16x8*)(ap + 16 * S3 + kk * 32);
        #pragma unroll
        for (int ni = 0; ni < 4; ni++) {
          bf16x8 bfrag = *(const bf16x8*)(bp + ni * 16 * S3 + kk * 32);
          acc[0][ni] = __builtin_amdgcn_mfma_f32_16x16x32_bf16(a0, bfrag, acc[0][ni], 0, 0, 0);
          acc[1][ni] = __builtin_amdgcn_mfma_f32_16x16x32_bf16(a1, bfrag, acc[1][ni], 0, 0, 0);
        }
      }
    }
    __syncthreads();
    unsigned short* h3 = &As[0][0];   // 64*SH3 = 8448 shorts <= 2*64*72 = 9216
    #pragma unroll
    for (int mi = 0; mi < 2; mi++)
      #pragma unroll
      for (int ni = 0; ni < 4; ni++)
        #pragma unroll
        for (int j = 0; j < 4; j++) {
          int r = wr + mi * 16 + fq * 4 + j;
          int col = wc + ni * 16 + fr;
          h3[r * SH3 + col] = f2bf(fmaxf(acc[mi][ni][j], 0.f));
        }
    __syncthreads();
    if (tid < 128) {
      for (int r = 0; r < 64; r++)
        pools[posb[r] * 128 + tid] += bf2f(h3[r * SH3 + tid]);
    }
  }
  __syncthreads();
  // zero-atomic flush: private partial slice per block
  for (int j = tid; j < 2048; j += 256)
    partial[(size_t)blockIdx.x * 2048 + j] = pools[j];
}

// ---------------- red: parallel partial reduction (128 blocks) ----------------
__global__ __launch_bounds__(256) void k_red(
    const float* __restrict__ partial, float* __restrict__ pooled) {
  __shared__ float red[256];
  int o = blockIdx.x * 16 + (threadIdx.x & 15);
  int sl = threadIdx.x >> 4;
  float s = 0.f;
  for (int g = sl; g < G3; g += 16) s += partial[(size_t)g * 2048 + o];
  red[threadIdx.x] = s;
  __syncthreads();
  if (threadIdx.x < 16) {
    float t = 0.f;
    #pragma unroll
    for (int k = 0; k < 16; k++) t += red[k * 16 + threadIdx.x];
    pooled[o] = t;
  }
}

// ---------------- fin: divide, linear, relu, softmax ----------------
__global__ void k_fin(const float* __restrict__ pooled, const float* __restrict__ cnt,
                      const float* __restrict__ wl, const float* __restrict__ bl,
                      float* __restrict__ out) {
  __shared__ float pr[128];
  __shared__ float lg[10];
  int b = blockIdx.x;
  int tid = threadIdx.x;
  pr[tid] = pooled[b * 128 + tid] / fmaxf(cnt[b], 1.0f);
  __syncthreads();
  if (tid < 10) {
    float acc = bl[tid];
    for (int j = 0; j < 128; j++) acc += pr[j] * wl[tid * 128 + j];
    lg[tid] = fmaxf(acc, 0.f);
  }
  __syncthreads();
  if (tid == 0) {
    float mx = lg[0];
    for (int k = 1; k < 10; k++) mx = fmaxf(mx, lg[k]);
    float se = 0.f;
    for (int k = 0; k < 10; k++) se += expf(lg[k] - mx);
    for (int k = 0; k < 10; k++) out[b * 10 + k] = expf(lg[k] - mx) / se;
  }
}

extern "C" void kernel_launch(void* const* d_in, const int* in_sizes, int n_in,
                              void* d_out, int out_size, void* d_ws, size_t ws_size,
                              hipStream_t stream) {
  const float* x  = (const float*)d_in[0];
  const float* w1 = (const float*)d_in[1];
  const float* w2 = (const float*)d_in[2];
  const float* w3 = (const float*)d_in[3];
  const float* wl = (const float*)d_in[4];
  const float* bl = (const float*)d_in[5];
  float* out = (float*)d_out;

  float* ws = (float*)d_ws;
  int* counter1 = (int*)(ws + 0);
  int* counter2 = (int*)(ws + 1);
  float* cnt = ws + 16;             // 16 floats
  float* pooled = ws + 32;          // 2048 floats (fully written by k_red)
  size_t off = 2080;                // 8B aligned
  unsigned long long* b1 = (unsigned long long*)(ws + off); off += NW1 * 2 + 2;
  unsigned long long* b2 = (unsigned long long*)(ws + off); off += NW2 * 2;
  int* wb1 = (int*)(ws + off); off += NW1;
  int* wb2 = (int*)(ws + off); off += NW2;
  int* idx1 = (int*)(ws + off); off += NP1;
  unsigned short* h1c = (unsigned short*)(ws + off); off += (size_t)CAP1 * 16;
  int* idx2 = (int*)(ws + off); off += NP2;
  int* list2 = (int*)(ws + off); off += CAP2;
  unsigned short* h2c = (unsigned short*)(ws + off); off += (size_t)CAP2 * 32;
  unsigned short* w2b = (unsigned short*)(ws + off); off += 128000;
  unsigned short* w3b = (unsigned short*)(ws + off); off += 110592;
  float* partial = ws + off; off += (size_t)G3 * 2048;

  hipMemsetAsync(d_ws, 0, 256, stream);  // counters + cnt

  k_tw2b<<<(256000 + 255) / 256, 256, 0, stream>>>(w2, w2b);
  k_tw3b<<<(221184 + 255) / 256, 256, 0, stream>>>(w3, w3b);
  k_ballot1<<<NP1 / 256, 256, 0, stream>>>(x, b1);
  k_ballot2<<<(NP2 + 255) / 256, 256, 0, stream>>>(b1, b2);
  k_scan<<<1, 1024, 0, stream>>>(b1, b2, wb1, wb2, counter1, counter2, cnt);
  k_conv1e<<<2048, 256, 0, stream>>>(x, w1, b1, wb1, h1c);
  k_fill1<<<NP1 / 256, 256, 0, stream>>>(b1, wb1, idx1);
  k_fill2<<<(NP2 + 255) / 256, 256, 0, stream>>>(b2, wb2, idx2, list2);
  k_conv2m<<<G2, 256, 0, stream>>>(h1c, w2b, idx1, list2, counter2, h2c);
  k_conv3m<<<G3, 256, 0, stream>>>(h2c, w3b, idx2, list2, counter2, partial);
  k_red<<<128, 256, 0, stream>>>(partial, pooled);
  k_fin<<<16, 128, 0, stream>>>(pooled, cnt, wl, bl, out);
}

// Round 17
// 385.989 us; speedup vs baseline: 1.3335x; 1.3335x over previous
//
#include <hip/hip_runtime.h>

#define BB 16
#define TT 128
#define HH 34
#define WW 34
#define HWSZ (HH*WW)                 // 1156
#define NP1 (BB*TT*HH*WW)            // 2367488
#define TD 64
#define HD 17
#define WD 17
#define NP2 (BB*TD*HD*WD)            // 295936
#define NW1 (NP1/64)                 // 36992
#define NW2 (NP2/64)                 // 4624
#define CAP1 262144
#define CAP2 131072
#define G2 1536
#define G3 512

typedef __attribute__((ext_vector_type(8))) short bf16x8;
typedef __attribute__((ext_vector_type(4))) float f32x4;

__device__ inline unsigned short f2bf(float f) {
  unsigned u = __float_as_uint(f);
  unsigned r = (u + 0x7fff + ((u >> 16) & 1)) >> 16;
  return (unsigned short)r;
}
__device__ inline float bf2f(unsigned short s) {
  return __uint_as_float((unsigned)s << 16);
}

// ---------------- ballot1 ----------------
__global__ void k_ballot1(const float* __restrict__ x, unsigned long long* __restrict__ b1) {
  int i = blockIdx.x * 256 + threadIdx.x;
  int hw = i % HWSZ;
  int bt = i / HWSZ;
  const float* px = x + (size_t)bt * 2 * HWSZ + hw;
  bool act = (fabsf(px[0]) + fabsf(px[HWSZ])) > 0.0f;
  unsigned long long m = __ballot(act);
  if ((threadIdx.x & 63) == 0) b1[i >> 6] = m;
}

// ---------------- ballot2 ----------------
__global__ void k_ballot2(const unsigned long long* __restrict__ b1,
                          unsigned long long* __restrict__ b2) {
  int i = blockIdx.x * 256 + threadIdx.x;
  if (i >= NP2) return;
  int ow = i % WD; int r = i / WD;
  int oh = r % HD; r /= HD;
  int od = r % TD; int b = r / TD;
  bool act = false;
  for (int dt = 0; dt < 2; dt++)
    for (int dh = 0; dh < 2; dh++)
      for (int dw = 0; dw < 2; dw++) {
        int t = od * 2 + dt, h = oh * 2 + dh, w = ow * 2 + dw;
        int lin = ((b * TT + t) * HH + h) * WW + w;
        if ((b1[lin >> 6] >> (lin & 63)) & 1ull) act = true;
      }
  unsigned long long m = __ballot(act);
  if ((threadIdx.x & 63) == 0) b2[i >> 6] = m;
}

// ---------------- scan ----------------
__global__ __launch_bounds__(1024) void k_scan(
    const unsigned long long* __restrict__ b1, const unsigned long long* __restrict__ b2,
    int* __restrict__ wb1, int* __restrict__ wb2,
    int* __restrict__ counter1, int* __restrict__ counter2, float* __restrict__ cnt) {
  __shared__ int wsum[16];
  __shared__ int wpre[16];
  __shared__ int tots[2];
  int tid = threadIdx.x, lane = tid & 63, wv = tid >> 6;

  const int CH1 = (NW1 + 1023) / 1024;
  int lo = tid * CH1, hi = min(lo + CH1, NW1);
  int s = 0;
  for (int i = lo; i < hi; i++) s += __popcll(b1[i]);
  int sc = s;
  #pragma unroll
  for (int d = 1; d < 64; d <<= 1) { int y = __shfl_up(sc, d); if (lane >= d) sc += y; }
  if (lane == 63) wsum[wv] = sc;
  __syncthreads();
  if (wv == 0 && lane < 16) {
    int v = wsum[lane];
    int p = v;
    #pragma unroll
    for (int d = 1; d < 16; d <<= 1) { int y = __shfl_up(p, d); if (lane >= d) p += y; }
    wpre[lane] = p - v;
    if (lane == 15) tots[0] = p;
  }
  __syncthreads();
  {
    int base = wpre[wv] + (sc - s);
    for (int i = lo; i < hi; i++) { wb1[i] = base; base += __popcll(b1[i]); }
  }
  if (tid == 0) *counter1 = tots[0];
  __syncthreads();

  const int CH2 = (NW2 + 1023) / 1024;
  lo = tid * CH2; hi = min(lo + CH2, NW2);
  s = 0;
  for (int i = lo; i < hi; i++) s += __popcll(b2[i]);
  sc = s;
  #pragma unroll
  for (int d = 1; d < 64; d <<= 1) { int y = __shfl_up(sc, d); if (lane >= d) sc += y; }
  if (lane == 63) wsum[wv] = sc;
  __syncthreads();
  if (wv == 0 && lane < 16) {
    int v = wsum[lane];
    int p = v;
    #pragma unroll
    for (int d = 1; d < 16; d <<= 1) { int y = __shfl_up(p, d); if (lane >= d) p += y; }
    wpre[lane] = p - v;
    if (lane == 15) tots[1] = p;
  }
  __syncthreads();
  {
    int base = wpre[wv] + (sc - s);
    for (int i = lo; i < hi; i++) { wb2[i] = base; base += __popcll(b2[i]); }
  }
  if (tid == 0) *counter2 = tots[1];
  __syncthreads();
  if (tid < 16) {
    int c0 = wb2[tid * 289];
    int c1 = (tid == 15) ? tots[1] : wb2[(tid + 1) * 289];
    cnt[tid] = (float)(c1 - c0);
  }
}

// ---------------- fill1 ----------------
__global__ void k_fill1(const unsigned long long* __restrict__ b1,
                        const int* __restrict__ wb1, int* __restrict__ idx1) {
  int i = blockIdx.x * 256 + threadIdx.x;
  unsigned long long m = b1[i >> 6];
  int lane = i & 63;
  int p = -1;
  if ((m >> lane) & 1ull) {
    p = wb1[i >> 6] + __popcll(m & ((1ull << lane) - 1ull));
    if (p >= CAP1) p = -1;
  }
  idx1[i] = p;
}

// ---------------- fill2 ----------------
__global__ void k_fill2(const unsigned long long* __restrict__ b2,
                        const int* __restrict__ wb2,
                        int* __restrict__ idx2, int* __restrict__ list2) {
  int i = blockIdx.x * 256 + threadIdx.x;
  if (i >= NP2) return;
  unsigned long long m = b2[i >> 6];
  int lane = i & 63;
  int p = -1;
  if ((m >> lane) & 1ull) {
    p = wb2[i >> 6] + __popcll(m & ((1ull << lane) - 1ull));
    if (p < CAP2) list2[p] = i; else p = -1;
  }
  idx2[i] = p;
}

// ---------------- conv1: event-queue per position ----------------
__global__ __launch_bounds__(256) void k_conv1e(
    const float* __restrict__ x, const float* __restrict__ w1,
    const unsigned long long* __restrict__ b1, const int* __restrict__ wb1,
    unsigned short* __restrict__ h1c) {
  __shared__ unsigned short w1s[8000];
  __shared__ unsigned int plist[384];
  __shared__ unsigned long long q[4][128];
  __shared__ int pcnt;
  int tid = threadIdx.x;
  int b = blockIdx.x >> 7;
  int t0 = blockIdx.x & 127;
  if (tid == 0) pcnt = 0;
  for (int j = tid; j < 8000; j += 256) w1s[j] = f2bf(w1[j]);
  __syncthreads();
  int slabbase = (b * TT + t0) * HWSZ;
  for (int hw = tid; hw < HWSZ; hw += 256) {
    int lin = slabbase + hw;
    unsigned long long m = b1[lin >> 6];
    int ln = lin & 63;
    if ((m >> ln) & 1ull) {
      int p = wb1[lin >> 6] + __popcll(m & ((1ull << ln) - 1ull));
      if (p < CAP1) {
        int s = atomicAdd(&pcnt, 1);
        if (s < 384) plist[s] = ((unsigned)p << 11) | (unsigned)hw;
      }
    }
  }
  __syncthreads();
  int n = min(pcnt, 384);
  int lane = tid & 63, wid = tid >> 6;
  int oc = lane & 31, c = lane >> 5;
  int woff = (oc * 2 + c) * 125;
  int csh = c * 16;
  int kt = lane / 5, kh = lane - kt * 5;
  const float* xb = x + (size_t)b * TT * 2 * HWSZ;
  for (int li = wid; li < n; li += 4) {
    unsigned e = plist[li];
    int hw = e & 0x7ff;
    int p = e >> 11;
    int h_ = hw / 34, w_ = hw - h_ * 34;
    int cntA = 0;
    unsigned m5 = 0;
    int t2 = 0, h2 = 0;
    if (lane < 25) {
      t2 = t0 + kt - 2;
      h2 = h_ + kh - 2;
      if ((unsigned)t2 < TT && (unsigned)h2 < HH) {
        int kwmin = (w_ < 2) ? (2 - w_) : 0;
        int kwmax = (w_ > 31) ? (35 - w_) : 4;
        int lin = ((b * TT + t2) * HH + h2) * WW + (w_ + kwmin - 2);
        int wi = lin >> 6, sh = lin & 63;
        unsigned long long v = b1[wi] >> sh;
        if (sh > 59) v |= b1[wi + 1] << (64 - sh);
        m5 = ((unsigned)v & ((1u << (kwmax - kwmin + 1)) - 1u)) << kwmin;
        cntA = __popc(m5);
      }
    }
    int inc = cntA;
    #pragma unroll
    for (int d = 1; d < 64; d <<= 1) { int y = __shfl_up(inc, d); if (lane >= d) inc += y; }
    int off = inc - cntA;
    int ne = __shfl(inc, 63);
    unsigned mm = m5;
    while (mm) {
      int kw = __ffs(mm) - 1; mm &= mm - 1;
      int w2 = w_ + kw - 2;
      int xoff = (t2 * 2) * HWSZ + h2 * 34 + w2;
      unsigned short xv0 = f2bf(xb[xoff]);
      unsigned short xv1 = f2bf(xb[xoff + HWSZ]);
      int tap = (kt * 5 + kh) * 5 + kw;
      q[wid][off++] = (unsigned long long)((unsigned)xv0 | ((unsigned)xv1 << 16)) |
                      ((unsigned long long)tap << 32);
    }
    float acc = 0.f;
    for (int e2 = 0; e2 < ne; e2++) {
      unsigned long long ent = q[wid][e2];
      int tap = (int)(ent >> 32);
      float xv = bf2f((unsigned short)((ent >> csh) & 0xffffull));
      acc += xv * bf2f(w1s[woff + tap]);
    }
    float other = __shfl_down(acc, 32);
    if (lane < 32) h1c[(size_t)p * 32 + oc] = f2bf(acc + other);
  }
}

// ---------------- weight transposes to bf16 [tap][oc][c] ----------------
__global__ void k_tw2b(const float* __restrict__ w2, unsigned short* __restrict__ w2b) {
  int i = blockIdx.x * blockDim.x + threadIdx.x;
  if (i >= 125 * 64 * 32) return;
  int c = i & 31; int r = i >> 5;
  int oc = r & 63; int tap = r >> 6;
  w2b[i] = f2bf(w2[((size_t)oc * 32 + c) * 125 + tap]);
}
__global__ void k_tw3b(const float* __restrict__ w3, unsigned short* __restrict__ w3b) {
  int i = blockIdx.x * blockDim.x + threadIdx.x;
  if (i >= 27 * 128 * 64) return;
  int c = i & 63; int r = i >> 6;
  int oc = r & 127; int tap = r >> 7;
  w3b[i] = f2bf(w3[((size_t)oc * 64 + c) * 27 + tap]);
}

// ---------------- conv2 MFMA: M=64, low-LDS (22KB), high cross-block TLP ----
#define S2 40
#define M2 64
__global__ __launch_bounds__(256) void k_conv2m(
    const unsigned short* __restrict__ h1c,   // [CAP1][32] bf16
    const unsigned short* __restrict__ w2b,   // [125][64][32] bf16
    const int* __restrict__ idx1,
    const int* __restrict__ list2, const int* __restrict__ counter2,
    unsigned short* __restrict__ h2c) {       // [CAP2][64] bf16
  __shared__ __align__(16) unsigned short As[2][M2 * S2];  // 10240 B
  __shared__ __align__(16) unsigned short Bs[2][64 * S2];  // 10240 B
  __shared__ int4 mc[M2];                                  // 1024 B
  __shared__ int klut[125];
  int tid = threadIdx.x;
  int lane = tid & 63, wid = tid >> 6;
  int fr = lane & 15, fq = lane >> 4;
  int wr = (wid >> 1) * 32, wc = (wid & 1) * 32;
  if (tid < 125) {
    int kt = tid / 25, r2 = tid - kt * 25;
    klut[tid] = kt | ((r2 / 5) << 4) | ((r2 % 5) << 8);
  }
  int count2 = min(*counter2, CAP2);
  int nchunk = (count2 + M2 - 1) >> 6;
  int spos = tid >> 2, sq = tid & 3;     // staging: 4 thr/row, 16B each
  // XCD swizzle (G2 % 8 == 0)
  int chid = (blockIdx.x & 7) * (G2 >> 3) + (blockIdx.x >> 3);
  __syncthreads();
  for (int ch = chid; ch < nchunk; ch += gridDim.x) {
    __syncthreads();
    if (tid < M2) {
      int p = ch * M2 + tid;
      int m = (p < count2) ? list2[p] : -1;
      int4 qq; qq.x = -1; qq.y = 0; qq.z = 0; qq.w = 0;
      if (m >= 0) {
        int ow = m % WD; int r = m / WD;
        int oh = r % HD; r /= HD;
        qq.x = r / TD; qq.y = r % TD; qq.z = oh; qq.w = ow;
      }
      mc[tid] = qq;
    }
    __syncthreads();
    int4 q = mc[spos];
    int tb = q.y * 2 - 2, hb = q.z * 2 - 2, wbv = q.w * 2 - 2;
    bool bok = q.x >= 0;
    auto rowfor = [&](int tap) -> int {
      int k = klut[tap];
      int t = tb + (k & 15), h = hb + ((k >> 4) & 15), w = wbv + (k >> 8);
      int row = -1;
      if (bok && (unsigned)t < TT && (unsigned)h < HH && (unsigned)w < WW)
        row = idx1[((q.x * TT + t) * HH + h) * WW + w];
      return row;
    };
    f32x4 acc[2][2];
    #pragma unroll
    for (int i = 0; i < 2; i++)
      #pragma unroll
      for (int j = 0; j < 2; j++) acc[i][j] = (f32x4){0.f, 0.f, 0.f, 0.f};
    // prefetch tap 0 data + tap 1 row
    int rowN1;
    int4 rA = {0,0,0,0}, rB;
    {
      int r0 = rowfor(0);
      if (r0 >= 0) rA = *(const int4*)(h1c + (size_t)r0 * 32 + sq * 8);
      rB = *(const int4*)(w2b + (size_t)spos * 32 + sq * 8);
      rowN1 = rowfor(1);
    }
    for (int tap = 0; tap < 125; ++tap) {
      int bsel = tap & 1;
      *(int4*)(&As[bsel][spos * S2 + sq * 8]) = rA;
      *(int4*)(&Bs[bsel][spos * S2 + sq * 8]) = rB;
      bool more = tap < 124;
      if (more) {
        int4 v = {0,0,0,0};
        if (rowN1 >= 0) v = *(const int4*)(h1c + (size_t)rowN1 * 32 + sq * 8);
        rA = v;
        rB = *(const int4*)(w2b + (size_t)(tap + 1) * 2048 + spos * 32 + sq * 8);
        rowN1 = (tap < 123) ? rowfor(tap + 2) : -1;
      }
      __syncthreads();
      const unsigned short* ap = &As[bsel][(wr + fr) * S2 + fq * 8];
      const unsigned short* bp = &Bs[bsel][(wc + fr) * S2 + fq * 8];
      bf16x8 a0 = *(const bf16x8*)ap;
      bf16x8 a1 = *(const bf16x8*)(ap + 16 * S2);
      bf16x8 b0 = *(const bf16x8*)bp;
      bf16x8 b1 = *(const bf16x8*)(bp + 16 * S2);
      acc[0][0] = __builtin_amdgcn_mfma_f32_16x16x32_bf16(a0, b0, acc[0][0], 0, 0, 0);
      acc[0][1] = __builtin_amdgcn_mfma_f32_16x16x32_bf16(a0, b1, acc[0][1], 0, 0, 0);
      acc[1][0] = __builtin_amdgcn_mfma_f32_16x16x32_bf16(a1, b0, acc[1][0], 0, 0, 0);
      acc[1][1] = __builtin_amdgcn_mfma_f32_16x16x32_bf16(a1, b1, acc[1][1], 0, 0, 0);
    }
    int base = ch * M2;
    #pragma unroll
    for (int mi = 0; mi < 2; mi++)
      #pragma unroll
      for (int ni = 0; ni < 2; ni++)
        #pragma unroll
        for (int j = 0; j < 4; j++) {
          int r = wr + mi * 16 + fq * 4 + j;
          int p = base + r;
          if (p < count2) {
            int col = wc + ni * 16 + fr;
            h2c[(size_t)p * 64 + col] = f2bf(fmaxf(acc[mi][ni][j], 0.f));
          }
        }
  }
}

// ---------------- conv3 MFMA (R14): As+Bs dbuf, rowsL, S3=72, h3 pooling ----
#define S3 72
#define SH3 132
__global__ __launch_bounds__(256) void k_conv3m(
    const unsigned short* __restrict__ h2c,   // [CAP2][64] bf16
    const unsigned short* __restrict__ w3b,   // [27][128][64] bf16
    const int* __restrict__ idx2,
    const int* __restrict__ list2, const int* __restrict__ counter2,
    float* __restrict__ partial) {            // [G3][2048] fp32
  __shared__ __align__(16) unsigned short As[2][64 * S3];   // 18432 B
  __shared__ __align__(16) unsigned short Bs[2][128 * S3];  // 36864 B
  __shared__ float pools[2048];
  __shared__ int rowsL[27 * 64];
  __shared__ int4 mc[64];
  __shared__ int posb[64];
  int tid = threadIdx.x;
  int lane = tid & 63, wid = tid >> 6;
  int fr = lane & 15, fq = lane >> 4;
  int wr = (wid >> 1) * 32, wc = (wid & 1) * 64;
  for (int j = tid; j < 2048; j += 256) pools[j] = 0.f;
  int count2 = min(*counter2, CAP2);
  int nchunk = (count2 + 63) >> 6;
  int spos = tid >> 2, sq = tid & 3;
  int boc = tid >> 1, bh = tid & 1;
  // XCD swizzle (G3 % 8 == 0)
  int chid = (blockIdx.x & 7) * (G3 >> 3) + (blockIdx.x >> 3);
  for (int ch = chid; ch < nchunk; ch += gridDim.x) {
    __syncthreads();
    if (tid < 64) {
      int p = ch * 64 + tid;
      int m = (p < count2) ? list2[p] : -1;
      int4 q; q.x = -1; q.y = 0; q.z = 0; q.w = 0;
      if (m >= 0) {
        int ow = m % WD; int r = m / WD;
        int oh = r % HD; r /= HD;
        q.x = r / TD; q.y = r % TD; q.z = oh; q.w = ow;
      }
      mc[tid] = q;
      posb[tid] = (q.x >= 0) ? q.x : 0;
    }
    __syncthreads();
    for (int j = tid; j < 27 * 64; j += 256) {
      int tap = j >> 6, pos = j & 63;
      int4 q = mc[pos];
      int row = -1;
      if (q.x >= 0) {
        int dt = tap / 9 - 1, dh = (tap / 3) % 3 - 1, dw = tap % 3 - 1;
        int t = q.y + dt, h = q.z + dh, w = q.w + dw;
        if ((unsigned)t < TD && (unsigned)h < HD && (unsigned)w < WD)
          row = idx2[((q.x * TD + t) * HD + h) * WD + w];
      }
      rowsL[j] = row;
    }
    __syncthreads();
    f32x4 acc[2][4];
    #pragma unroll
    for (int i = 0; i < 2; i++)
      #pragma unroll
      for (int j = 0; j < 4; j++) acc[i][j] = (f32x4){0.f, 0.f, 0.f, 0.f};
    int4 rA0 = {0, 0, 0, 0}, rA1 = {0, 0, 0, 0};
    {
      int row = rowsL[spos];
      if (row >= 0) {
        const unsigned short* s = h2c + (size_t)row * 64 + sq * 16;
        rA0 = *(const int4*)s;
        rA1 = *(const int4*)(s + 8);
      }
    }
    int4 rB0, rB1, rB2, rB3;
    {
      const unsigned short* wsrc = w3b + (size_t)boc * 64 + bh * 32;
      rB0 = *(const int4*)(wsrc);
      rB1 = *(const int4*)(wsrc + 8);
      rB2 = *(const int4*)(wsrc + 16);
      rB3 = *(const int4*)(wsrc + 24);
    }
    for (int tap = 0; tap < 27; tap++) {
      int bsel = tap & 1;
      {
        unsigned short* ad = &As[bsel][spos * S3 + sq * 16];
        *(int4*)(ad) = rA0;
        *(int4*)(ad + 8) = rA1;
        unsigned short* bd = &Bs[bsel][boc * S3 + bh * 32];
        *(int4*)(bd) = rB0;
        *(int4*)(bd + 8) = rB1;
        *(int4*)(bd + 16) = rB2;
        *(int4*)(bd + 24) = rB3;
      }
      if (tap < 26) {
        int row = rowsL[(tap + 1) * 64 + spos];
        int4 v0 = {0, 0, 0, 0}, v1 = {0, 0, 0, 0};
        if (row >= 0) {
          const unsigned short* s = h2c + (size_t)row * 64 + sq * 16;
          v0 = *(const int4*)s;
          v1 = *(const int4*)(s + 8);
        }
        rA0 = v0; rA1 = v1;
        const unsigned short* wsrc = w3b + ((size_t)(tap + 1) * 128 + boc) * 64 + bh * 32;
        rB0 = *(const int4*)(wsrc);
        rB1 = *(const int4*)(wsrc + 8);
        rB2 = *(const int4*)(wsrc + 16);
        rB3 = *(const int4*)(wsrc + 24);
      }
      __syncthreads();
      const unsigned short* ap = &As[bsel][(wr + fr) * S3 + fq * 8];
      const unsigned short* bp = &Bs[bsel][(wc + fr) * S3 + fq * 8];
      #pragma unroll
      for (int kk = 0; kk < 2; kk++) {
        bf16x8 a0 = *(const bf16x8*)(ap + kk * 32);
        bf16x8 a1 = *(const bf16x8*)(ap + 16 * S3 + kk * 32);
        #pragma unroll
        for (int ni = 0; ni < 4; ni++) {
          bf16x8 bfrag = *(const bf16x8*)(bp + ni * 16 * S3 + kk * 32);
          acc[0][ni] = __builtin_amdgcn_mfma_f32_16x16x32_bf16(a0, bfrag, acc[0][ni], 0, 0, 0);
          acc[1][ni] = __builtin_amdgcn_mfma_f32_16x16x32_bf16(a1, bfrag, acc[1][ni], 0, 0, 0);
        }
      }
    }
    __syncthreads();
    unsigned short* h3 = &As[0][0];   // 64*SH3 = 8448 shorts <= 2*64*72 = 9216
    #pragma unroll
    for (int mi = 0; mi < 2; mi++)
      #pragma unroll
      for (int ni = 0; ni < 4; ni++)
        #pragma unroll
        for (int j = 0; j < 4; j++) {
          int r = wr + mi * 16 + fq * 4 + j;
          int col = wc + ni * 16 + fr;
          h3[r * SH3 + col] = f2bf(fmaxf(acc[mi][ni][j], 0.f));
        }
    __syncthreads();
    if (tid < 128) {
      for (int r = 0; r < 64; r++)
        pools[posb[r] * 128 + tid] += bf2f(h3[r * SH3 + tid]);
    }
  }
  __syncthreads();
  // zero-atomic flush: private partial slice per block
  for (int j = tid; j < 2048; j += 256)
    partial[(size_t)blockIdx.x * 2048 + j] = pools[j];
}

// ---------------- red: parallel partial reduction (128 blocks) ----------------
__global__ __launch_bounds__(256) void k_red(
    const float* __restrict__ partial, float* __restrict__ pooled) {
  __shared__ float red[256];
  int o = blockIdx.x * 16 + (threadIdx.x & 15);
  int sl = threadIdx.x >> 4;
  float s = 0.f;
  for (int g = sl; g < G3; g += 16) s += partial[(size_t)g * 2048 + o];
  red[threadIdx.x] = s;
  __syncthreads();
  if (threadIdx.x < 16) {
    float t = 0.f;
    #pragma unroll
    for (int k = 0; k < 16; k++) t += red[k * 16 + threadIdx.x];
    pooled[o] = t;
  }
}

// ---------------- fin: divide, linear, relu, softmax ----------------
__global__ void k_fin(const float* __restrict__ pooled, const float* __restrict__ cnt,
                      const float* __restrict__ wl, const float* __restrict__ bl,
                      float* __restrict__ out) {
  __shared__ float pr[128];
  __shared__ float lg[10];
  int b = blockIdx.x;
  int tid = threadIdx.x;
  pr[tid] = pooled[b * 128 + tid] / fmaxf(cnt[b], 1.0f);
  __syncthreads();
  if (tid < 10) {
    float acc = bl[tid];
    for (int j = 0; j < 128; j++) acc += pr[j] * wl[tid * 128 + j];
    lg[tid] = fmaxf(acc, 0.f);
  }
  __syncthreads();
  if (tid == 0) {
    float mx = lg[0];
    for (int k = 1; k < 10; k++) mx = fmaxf(mx, lg[k]);
    float se = 0.f;
    for (int k = 0; k < 10; k++) se += expf(lg[k] - mx);
    for (int k = 0; k < 10; k++) out[b * 10 + k] = expf(lg[k] - mx) / se;
  }
}

extern "C" void kernel_launch(void* const* d_in, const int* in_sizes, int n_in,
                              void* d_out, int out_size, void* d_ws, size_t ws_size,
                              hipStream_t stream) {
  const float* x  = (const float*)d_in[0];
  const float* w1 = (const float*)d_in[1];
  const float* w2 = (const float*)d_in[2];
  const float* w3 = (const float*)d_in[3];
  const float* wl = (const float*)d_in[4];
  const float* bl = (const float*)d_in[5];
  float* out = (float*)d_out;

  float* ws = (float*)d_ws;
  int* counter1 = (int*)(ws + 0);
  int* counter2 = (int*)(ws + 1);
  float* cnt = ws + 16;             // 16 floats
  float* pooled = ws + 32;          // 2048 floats (fully written by k_red)
  size_t off = 2080;                // 8B aligned
  unsigned long long* b1 = (unsigned long long*)(ws + off); off += NW1 * 2 + 2;
  unsigned long long* b2 = (unsigned long long*)(ws + off); off += NW2 * 2;
  int* wb1 = (int*)(ws + off); off += NW1;
  int* wb2 = (int*)(ws + off); off += NW2;
  int* idx1 = (int*)(ws + off); off += NP1;
  unsigned short* h1c = (unsigned short*)(ws + off); off += (size_t)CAP1 * 16;
  int* idx2 = (int*)(ws + off); off += NP2;
  int* list2 = (int*)(ws + off); off += CAP2;
  unsigned short* h2c = (unsigned short*)(ws + off); off += (size_t)CAP2 * 32;
  unsigned short* w2b = (unsigned short*)(ws + off); off += 128000;
  unsigned short* w3b = (unsigned short*)(ws + off); off += 110592;
  float* partial = ws + off; off += (size_t)G3 * 2048;

  hipMemsetAsync(d_ws, 0, 256, stream);  // counters + cnt

  k_tw2b<<<(256000 + 255) / 256, 256, 0, stream>>>(w2, w2b);
  k_tw3b<<<(221184 + 255) / 256, 256, 0, stream>>>(w3, w3b);
  k_ballot1<<<NP1 / 256, 256, 0, stream>>>(x, b1);
  k_ballot2<<<(NP2 + 255) / 256, 256, 0, stream>>>(b1, b2);
  k_scan<<<1, 1024, 0, stream>>>(b1, b2, wb1, wb2, counter1, counter2, cnt);
  k_conv1e<<<2048, 256, 0, stream>>>(x, w1, b1, wb1, h1c);
  k_fill1<<<NP1 / 256, 256, 0, stream>>>(b1, wb1, idx1);
  k_fill2<<<(NP2 + 255) / 256, 256, 0, stream>>>(b2, wb2, idx2, list2);
  k_conv2m<<<G2, 256, 0, stream>>>(h1c, w2b, idx1, list2, counter2, h2c);
  k_conv3m<<<G3, 256, 0, stream>>>(h2c, w3b, idx2, list2, counter2, partial);
  k_red<<<128, 256, 0, stream>>>(partial, pooled);
  k_fin<<<16, 128, 0, stream>>>(pooled, cnt, wl, bl, out);
}

// Round 18
// 376.580 us; speedup vs baseline: 1.3668x; 1.0250x over previous
//
#include <hip/hip_runtime.h>

#define BB 16
#define TT 128
#define HH 34
#define WW 34
#define HWSZ (HH*WW)                 // 1156
#define NP1 (BB*TT*HH*WW)            // 2367488
#define TD 64
#define HD 17
#define WD 17
#define NP2 (BB*TD*HD*WD)            // 295936
#define NW1 (NP1/64)                 // 36992
#define NW2 (NP2/64)                 // 4624
#define CAP1 262144
#define CAP2 131072
#define G2 1024
#define G3 512

typedef __attribute__((ext_vector_type(8))) short bf16x8;
typedef __attribute__((ext_vector_type(4))) float f32x4;

__device__ inline unsigned short f2bf(float f) {
  unsigned u = __float_as_uint(f);
  unsigned r = (u + 0x7fff + ((u >> 16) & 1)) >> 16;
  return (unsigned short)r;
}
__device__ inline float bf2f(unsigned short s) {
  return __uint_as_float((unsigned)s << 16);
}

// ---------------- ballot1 ----------------
__global__ void k_ballot1(const float* __restrict__ x, unsigned long long* __restrict__ b1) {
  int i = blockIdx.x * 256 + threadIdx.x;
  int hw = i % HWSZ;
  int bt = i / HWSZ;
  const float* px = x + (size_t)bt * 2 * HWSZ + hw;
  bool act = (fabsf(px[0]) + fabsf(px[HWSZ])) > 0.0f;
  unsigned long long m = __ballot(act);
  if ((threadIdx.x & 63) == 0) b1[i >> 6] = m;
}

// ---------------- ballot2 ----------------
__global__ void k_ballot2(const unsigned long long* __restrict__ b1,
                          unsigned long long* __restrict__ b2) {
  int i = blockIdx.x * 256 + threadIdx.x;
  if (i >= NP2) return;
  int ow = i % WD; int r = i / WD;
  int oh = r % HD; r /= HD;
  int od = r % TD; int b = r / TD;
  bool act = false;
  for (int dt = 0; dt < 2; dt++)
    for (int dh = 0; dh < 2; dh++)
      for (int dw = 0; dw < 2; dw++) {
        int t = od * 2 + dt, h = oh * 2 + dh, w = ow * 2 + dw;
        int lin = ((b * TT + t) * HH + h) * WW + w;
        if ((b1[lin >> 6] >> (lin & 63)) & 1ull) act = true;
      }
  unsigned long long m = __ballot(act);
  if ((threadIdx.x & 63) == 0) b2[i >> 6] = m;
}

// ---------------- scan ----------------
__global__ __launch_bounds__(1024) void k_scan(
    const unsigned long long* __restrict__ b1, const unsigned long long* __restrict__ b2,
    int* __restrict__ wb1, int* __restrict__ wb2,
    int* __restrict__ counter1, int* __restrict__ counter2, float* __restrict__ cnt) {
  __shared__ int wsum[16];
  __shared__ int wpre[16];
  __shared__ int tots[2];
  int tid = threadIdx.x, lane = tid & 63, wv = tid >> 6;

  const int CH1 = (NW1 + 1023) / 1024;
  int lo = tid * CH1, hi = min(lo + CH1, NW1);
  int s = 0;
  for (int i = lo; i < hi; i++) s += __popcll(b1[i]);
  int sc = s;
  #pragma unroll
  for (int d = 1; d < 64; d <<= 1) { int y = __shfl_up(sc, d); if (lane >= d) sc += y; }
  if (lane == 63) wsum[wv] = sc;
  __syncthreads();
  if (wv == 0 && lane < 16) {
    int v = wsum[lane];
    int p = v;
    #pragma unroll
    for (int d = 1; d < 16; d <<= 1) { int y = __shfl_up(p, d); if (lane >= d) p += y; }
    wpre[lane] = p - v;
    if (lane == 15) tots[0] = p;
  }
  __syncthreads();
  {
    int base = wpre[wv] + (sc - s);
    for (int i = lo; i < hi; i++) { wb1[i] = base; base += __popcll(b1[i]); }
  }
  if (tid == 0) *counter1 = tots[0];
  __syncthreads();

  const int CH2 = (NW2 + 1023) / 1024;
  lo = tid * CH2; hi = min(lo + CH2, NW2);
  s = 0;
  for (int i = lo; i < hi; i++) s += __popcll(b2[i]);
  sc = s;
  #pragma unroll
  for (int d = 1; d < 64; d <<= 1) { int y = __shfl_up(sc, d); if (lane >= d) sc += y; }
  if (lane == 63) wsum[wv] = sc;
  __syncthreads();
  if (wv == 0 && lane < 16) {
    int v = wsum[lane];
    int p = v;
    #pragma unroll
    for (int d = 1; d < 16; d <<= 1) { int y = __shfl_up(p, d); if (lane >= d) p += y; }
    wpre[lane] = p - v;
    if (lane == 15) tots[1] = p;
  }
  __syncthreads();
  {
    int base = wpre[wv] + (sc - s);
    for (int i = lo; i < hi; i++) { wb2[i] = base; base += __popcll(b2[i]); }
  }
  if (tid == 0) *counter2 = tots[1];
  __syncthreads();
  if (tid < 16) {
    int c0 = wb2[tid * 289];
    int c1 = (tid == 15) ? tots[1] : wb2[(tid + 1) * 289];
    cnt[tid] = (float)(c1 - c0);
  }
}

// ---------------- fill1 ----------------
__global__ void k_fill1(const unsigned long long* __restrict__ b1,
                        const int* __restrict__ wb1, int* __restrict__ idx1) {
  int i = blockIdx.x * 256 + threadIdx.x;
  unsigned long long m = b1[i >> 6];
  int lane = i & 63;
  int p = -1;
  if ((m >> lane) & 1ull) {
    p = wb1[i >> 6] + __popcll(m & ((1ull << lane) - 1ull));
    if (p >= CAP1) p = -1;
  }
  idx1[i] = p;
}

// ---------------- fill2 ----------------
__global__ void k_fill2(const unsigned long long* __restrict__ b2,
                        const int* __restrict__ wb2,
                        int* __restrict__ idx2, int* __restrict__ list2) {
  int i = blockIdx.x * 256 + threadIdx.x;
  if (i >= NP2) return;
  unsigned long long m = b2[i >> 6];
  int lane = i & 63;
  int p = -1;
  if ((m >> lane) & 1ull) {
    p = wb2[i >> 6] + __popcll(m & ((1ull << lane) - 1ull));
    if (p < CAP2) list2[p] = i; else p = -1;
  }
  idx2[i] = p;
}

// ---------------- conv1: event-queue per position ----------------
__global__ __launch_bounds__(256) void k_conv1e(
    const float* __restrict__ x, const float* __restrict__ w1,
    const unsigned long long* __restrict__ b1, const int* __restrict__ wb1,
    unsigned short* __restrict__ h1c) {
  __shared__ unsigned short w1s[8000];
  __shared__ unsigned int plist[384];
  __shared__ unsigned long long q[4][128];
  __shared__ int pcnt;
  int tid = threadIdx.x;
  int b = blockIdx.x >> 7;
  int t0 = blockIdx.x & 127;
  if (tid == 0) pcnt = 0;
  for (int j = tid; j < 8000; j += 256) w1s[j] = f2bf(w1[j]);
  __syncthreads();
  int slabbase = (b * TT + t0) * HWSZ;
  for (int hw = tid; hw < HWSZ; hw += 256) {
    int lin = slabbase + hw;
    unsigned long long m = b1[lin >> 6];
    int ln = lin & 63;
    if ((m >> ln) & 1ull) {
      int p = wb1[lin >> 6] + __popcll(m & ((1ull << ln) - 1ull));
      if (p < CAP1) {
        int s = atomicAdd(&pcnt, 1);
        if (s < 384) plist[s] = ((unsigned)p << 11) | (unsigned)hw;
      }
    }
  }
  __syncthreads();
  int n = min(pcnt, 384);
  int lane = tid & 63, wid = tid >> 6;
  int oc = lane & 31, c = lane >> 5;
  int woff = (oc * 2 + c) * 125;
  int csh = c * 16;
  int kt = lane / 5, kh = lane - kt * 5;
  const float* xb = x + (size_t)b * TT * 2 * HWSZ;
  for (int li = wid; li < n; li += 4) {
    unsigned e = plist[li];
    int hw = e & 0x7ff;
    int p = e >> 11;
    int h_ = hw / 34, w_ = hw - h_ * 34;
    int cntA = 0;
    unsigned m5 = 0;
    int t2 = 0, h2 = 0;
    if (lane < 25) {
      t2 = t0 + kt - 2;
      h2 = h_ + kh - 2;
      if ((unsigned)t2 < TT && (unsigned)h2 < HH) {
        int kwmin = (w_ < 2) ? (2 - w_) : 0;
        int kwmax = (w_ > 31) ? (35 - w_) : 4;
        int lin = ((b * TT + t2) * HH + h2) * WW + (w_ + kwmin - 2);
        int wi = lin >> 6, sh = lin & 63;
        unsigned long long v = b1[wi] >> sh;
        if (sh > 59) v |= b1[wi + 1] << (64 - sh);
        m5 = ((unsigned)v & ((1u << (kwmax - kwmin + 1)) - 1u)) << kwmin;
        cntA = __popc(m5);
      }
    }
    int inc = cntA;
    #pragma unroll
    for (int d = 1; d < 64; d <<= 1) { int y = __shfl_up(inc, d); if (lane >= d) inc += y; }
    int off = inc - cntA;
    int ne = __shfl(inc, 63);
    unsigned mm = m5;
    while (mm) {
      int kw = __ffs(mm) - 1; mm &= mm - 1;
      int w2 = w_ + kw - 2;
      int xoff = (t2 * 2) * HWSZ + h2 * 34 + w2;
      unsigned short xv0 = f2bf(xb[xoff]);
      unsigned short xv1 = f2bf(xb[xoff + HWSZ]);
      int tap = (kt * 5 + kh) * 5 + kw;
      q[wid][off++] = (unsigned long long)((unsigned)xv0 | ((unsigned)xv1 << 16)) |
                      ((unsigned long long)tap << 32);
    }
    float acc = 0.f;
    for (int e2 = 0; e2 < ne; e2++) {
      unsigned long long ent = q[wid][e2];
      int tap = (int)(ent >> 32);
      float xv = bf2f((unsigned short)((ent >> csh) & 0xffffull));
      acc += xv * bf2f(w1s[woff + tap]);
    }
    float other = __shfl_down(acc, 32);
    if (lane < 32) h1c[(size_t)p * 32 + oc] = f2bf(acc + other);
  }
}

// ---------------- weight transposes to bf16 [tap][oc][c] ----------------
__global__ void k_tw2b(const float* __restrict__ w2, unsigned short* __restrict__ w2b) {
  int i = blockIdx.x * blockDim.x + threadIdx.x;
  if (i >= 125 * 64 * 32) return;
  int c = i & 31; int r = i >> 5;
  int oc = r & 63; int tap = r >> 6;
  w2b[i] = f2bf(w2[((size_t)oc * 32 + c) * 125 + tap]);
}
__global__ void k_tw3b(const float* __restrict__ w3, unsigned short* __restrict__ w3b) {
  int i = blockIdx.x * blockDim.x + threadIdx.x;
  if (i >= 27 * 128 * 64) return;
  int c = i & 63; int r = i >> 6;
  int oc = r & 127; int tap = r >> 7;
  w3b[i] = f2bf(w3[((size_t)oc * 64 + c) * 27 + tap]);
}

// ---------------- conv2 MFMA: M=128 tile, idx1 gather, S2=40 (16B-aligned) ----
#define S2 40
#define M2 128
__global__ __launch_bounds__(256) void k_conv2m(
    const unsigned short* __restrict__ h1c,   // [CAP1][32] bf16
    const unsigned short* __restrict__ w2b,   // [125][64][32] bf16
    const int* __restrict__ idx1,
    const int* __restrict__ list2, const int* __restrict__ counter2,
    unsigned short* __restrict__ h2c) {       // [CAP2][64] bf16
  __shared__ __align__(16) unsigned short As[2][M2 * S2];  // 20480 B
  __shared__ __align__(16) unsigned short Bs[2][64 * S2];  // 10240 B
  __shared__ int4 mc[M2];                                  // 2048 B
  __shared__ int klut[125];
  int tid = threadIdx.x;
  int lane = tid & 63, wid = tid >> 6;
  int fr = lane & 15, fq = lane >> 4;
  int wr = wid * 32;                 // wave owns rows [wr, wr+32), all 64 cols
  if (tid < 125) {
    int kt = tid / 25, r2 = tid - kt * 25;
    klut[tid] = kt | ((r2 / 5) << 4) | ((r2 % 5) << 8);
  }
  int count2 = min(*counter2, CAP2);
  int nchunk = (count2 + M2 - 1) >> 7;
  int aspos = tid >> 1, asq = tid & 1;   // A staging: 2 thr/row, 32B each
  int bspos = tid >> 2, bsq = tid & 3;   // B staging: 4 thr/row, 16B each
  // XCD swizzle (G2 % 8 == 0)
  int chid = (blockIdx.x & 7) * (G2 >> 3) + (blockIdx.x >> 3);
  __syncthreads();
  for (int ch = chid; ch < nchunk; ch += gridDim.x) {
    __syncthreads();
    if (tid < M2) {
      int p = ch * M2 + tid;
      int m = (p < count2) ? list2[p] : -1;
      int4 qq; qq.x = -1; qq.y = 0; qq.z = 0; qq.w = 0;
      if (m >= 0) {
        int ow = m % WD; int r = m / WD;
        int oh = r % HD; r /= HD;
        qq.x = r / TD; qq.y = r % TD; qq.z = oh; qq.w = ow;
      }
      mc[tid] = qq;
    }
    __syncthreads();
    int4 q = mc[aspos];
    int tb = q.y * 2 - 2, hb = q.z * 2 - 2, wbv = q.w * 2 - 2;
    bool bok = q.x >= 0;
    auto rowfor = [&](int tap) -> int {
      int k = klut[tap];
      int t = tb + (k & 15), h = hb + ((k >> 4) & 15), w = wbv + (k >> 8);
      int row = -1;
      if (bok && (unsigned)t < TT && (unsigned)h < HH && (unsigned)w < WW)
        row = idx1[((q.x * TT + t) * HH + h) * WW + w];
      return row;
    };
    f32x4 acc[2][4];
    #pragma unroll
    for (int i = 0; i < 2; i++)
      #pragma unroll
      for (int j = 0; j < 4; j++) acc[i][j] = (f32x4){0.f, 0.f, 0.f, 0.f};
    // prefetch tap 0 data + tap 1 row
    int rowN1;
    int4 rA0 = {0,0,0,0}, rA1 = {0,0,0,0}, rB;
    {
      int r0 = rowfor(0);
      if (r0 >= 0) {
        const unsigned short* s = h1c + (size_t)r0 * 32 + asq * 16;
        rA0 = *(const int4*)s;
        rA1 = *(const int4*)(s + 8);
      }
      rB = *(const int4*)(w2b + (size_t)bspos * 32 + bsq * 8);
      rowN1 = rowfor(1);
    }
    for (int tap = 0; tap < 125; ++tap) {
      int bsel = tap & 1;
      {
        unsigned short* ad = &As[bsel][aspos * S2 + asq * 16];
        *(int4*)(ad) = rA0;
        *(int4*)(ad + 8) = rA1;
        *(int4*)(&Bs[bsel][bspos * S2 + bsq * 8]) = rB;
      }
      bool more = tap < 124;
      if (more) {
        int4 v0 = {0,0,0,0}, v1 = {0,0,0,0};
        if (rowN1 >= 0) {
          const unsigned short* s = h1c + (size_t)rowN1 * 32 + asq * 16;
          v0 = *(const int4*)s;
          v1 = *(const int4*)(s + 8);
        }
        rA0 = v0; rA1 = v1;
        rB = *(const int4*)(w2b + (size_t)(tap + 1) * 2048 + bspos * 32 + bsq * 8);
        rowN1 = (tap < 123) ? rowfor(tap + 2) : -1;
      }
      __syncthreads();
      const unsigned short* ap = &As[bsel][(wr + fr) * S2 + fq * 8];
      const unsigned short* bp = &Bs[bsel][fr * S2 + fq * 8];
      bf16x8 a0 = *(const bf16x8*)ap;
      bf16x8 a1 = *(const bf16x8*)(ap + 16 * S2);
      #pragma unroll
      for (int ni = 0; ni < 4; ni++) {
        bf16x8 bfrag = *(const bf16x8*)(bp + ni * 16 * S2);
        acc[0][ni] = __builtin_amdgcn_mfma_f32_16x16x32_bf16(a0, bfrag, acc[0][ni], 0, 0, 0);
        acc[1][ni] = __builtin_amdgcn_mfma_f32_16x16x32_bf16(a1, bfrag, acc[1][ni], 0, 0, 0);
      }
    }
    int base = ch * M2;
    #pragma unroll
    for (int mi = 0; mi < 2; mi++)
      #pragma unroll
      for (int ni = 0; ni < 4; ni++)
        #pragma unroll
        for (int j = 0; j < 4; j++) {
          int r = wr + mi * 16 + fq * 4 + j;
          int p = base + r;
          if (p < count2) {
            int col = ni * 16 + fr;
            h2c[(size_t)p * 64 + col] = f2bf(fmaxf(acc[mi][ni][j], 0.f));
          }
        }
  }
}

// ---------------- conv3 MFMA: As+Bs dbuf, rowsL from idx2, S3=72, h3 pooling ----
#define S3 72
#define SH3 132
__global__ __launch_bounds__(256) void k_conv3m(
    const unsigned short* __restrict__ h2c,   // [CAP2][64] bf16
    const unsigned short* __restrict__ w3b,   // [27][128][64] bf16
    const int* __restrict__ idx2,
    const int* __restrict__ list2, const int* __restrict__ counter2,
    float* __restrict__ partial) {            // [G3][2048] fp32
  __shared__ __align__(16) unsigned short As[2][64 * S3];   // 18432 B
  __shared__ __align__(16) unsigned short Bs[2][128 * S3];  // 36864 B
  __shared__ float pools[2048];
  __shared__ int rowsL[27 * 64];
  __shared__ int4 mc[64];
  __shared__ int posb[64];
  int tid = threadIdx.x;
  int lane = tid & 63, wid = tid >> 6;
  int fr = lane & 15, fq = lane >> 4;
  int wr = (wid >> 1) * 32, wc = (wid & 1) * 64;
  for (int j = tid; j < 2048; j += 256) pools[j] = 0.f;
  int count2 = min(*counter2, CAP2);
  int nchunk = (count2 + 63) >> 6;
  int spos = tid >> 2, sq = tid & 3;
  int boc = tid >> 1, bh = tid & 1;
  // XCD swizzle (G3 % 8 == 0)
  int chid = (blockIdx.x & 7) * (G3 >> 3) + (blockIdx.x >> 3);
  for (int ch = chid; ch < nchunk; ch += gridDim.x) {
    __syncthreads();
    if (tid < 64) {
      int p = ch * 64 + tid;
      int m = (p < count2) ? list2[p] : -1;
      int4 q; q.x = -1; q.y = 0; q.z = 0; q.w = 0;
      if (m >= 0) {
        int ow = m % WD; int r = m / WD;
        int oh = r % HD; r /= HD;
        q.x = r / TD; q.y = r % TD; q.z = oh; q.w = ow;
      }
      mc[tid] = q;
      posb[tid] = (q.x >= 0) ? q.x : 0;
    }
    __syncthreads();
    for (int j = tid; j < 27 * 64; j += 256) {
      int tap = j >> 6, pos = j & 63;
      int4 q = mc[pos];
      int row = -1;
      if (q.x >= 0) {
        int dt = tap / 9 - 1, dh = (tap / 3) % 3 - 1, dw = tap % 3 - 1;
        int t = q.y + dt, h = q.z + dh, w = q.w + dw;
        if ((unsigned)t < TD && (unsigned)h < HD && (unsigned)w < WD)
          row = idx2[((q.x * TD + t) * HD + h) * WD + w];
      }
      rowsL[j] = row;
    }
    __syncthreads();
    f32x4 acc[2][4];
    #pragma unroll
    for (int i = 0; i < 2; i++)
      #pragma unroll
      for (int j = 0; j < 4; j++) acc[i][j] = (f32x4){0.f, 0.f, 0.f, 0.f};
    int4 rA0 = {0, 0, 0, 0}, rA1 = {0, 0, 0, 0};
    {
      int row = rowsL[spos];
      if (row >= 0) {
        const unsigned short* s = h2c + (size_t)row * 64 + sq * 16;
        rA0 = *(const int4*)s;
        rA1 = *(const int4*)(s + 8);
      }
    }
    int4 rB0, rB1, rB2, rB3;
    {
      const unsigned short* wsrc = w3b + (size_t)boc * 64 + bh * 32;
      rB0 = *(const int4*)(wsrc);
      rB1 = *(const int4*)(wsrc + 8);
      rB2 = *(const int4*)(wsrc + 16);
      rB3 = *(const int4*)(wsrc + 24);
    }
    for (int tap = 0; tap < 27; tap++) {
      int bsel = tap & 1;
      {
        unsigned short* ad = &As[bsel][spos * S3 + sq * 16];
        *(int4*)(ad) = rA0;
        *(int4*)(ad + 8) = rA1;
        unsigned short* bd = &Bs[bsel][boc * S3 + bh * 32];
        *(int4*)(bd) = rB0;
        *(int4*)(bd + 8) = rB1;
        *(int4*)(bd + 16) = rB2;
        *(int4*)(bd + 24) = rB3;
      }
      if (tap < 26) {
        int row = rowsL[(tap + 1) * 64 + spos];
        int4 v0 = {0, 0, 0, 0}, v1 = {0, 0, 0, 0};
        if (row >= 0) {
          const unsigned short* s = h2c + (size_t)row * 64 + sq * 16;
          v0 = *(const int4*)s;
          v1 = *(const int4*)(s + 8);
        }
        rA0 = v0; rA1 = v1;
        const unsigned short* wsrc = w3b + ((size_t)(tap + 1) * 128 + boc) * 64 + bh * 32;
        rB0 = *(const int4*)(wsrc);
        rB1 = *(const int4*)(wsrc + 8);
        rB2 = *(const int4*)(wsrc + 16);
        rB3 = *(const int4*)(wsrc + 24);
      }
      __syncthreads();
      const unsigned short* ap = &As[bsel][(wr + fr) * S3 + fq * 8];
      const unsigned short* bp = &Bs[bsel][(wc + fr) * S3 + fq * 8];
      #pragma unroll
      for (int kk = 0; kk < 2; kk++) {
        bf16x8 a0 = *(const bf16x8*)(ap + kk * 32);
        bf16x8 a1 = *(const bf16x8*)(ap + 16 * S3 + kk * 32);
        #pragma unroll
        for (int ni = 0; ni < 4; ni++) {
          bf16x8 bfrag = *(const bf16x8*)(bp + ni * 16 * S3 + kk * 32);
          acc[0][ni] = __builtin_amdgcn_mfma_f32_16x16x32_bf16(a0, bfrag, acc[0][ni], 0, 0, 0);
          acc[1][ni] = __builtin_amdgcn_mfma_f32_16x16x32_bf16(a1, bfrag, acc[1][ni], 0, 0, 0);
        }
      }
    }
    __syncthreads();
    unsigned short* h3 = &As[0][0];   // 64*SH3 = 8448 shorts <= 2*64*72 = 9216
    #pragma unroll
    for (int mi = 0; mi < 2; mi++)
      #pragma unroll
      for (int ni = 0; ni < 4; ni++)
        #pragma unroll
        for (int j = 0; j < 4; j++) {
          int r = wr + mi * 16 + fq * 4 + j;
          int col = wc + ni * 16 + fr;
          h3[r * SH3 + col] = f2bf(fmaxf(acc[mi][ni][j], 0.f));
        }
    __syncthreads();
    if (tid < 128) {
      for (int r = 0; r < 64; r++)
        pools[posb[r] * 128 + tid] += bf2f(h3[r * SH3 + tid]);
    }
  }
  __syncthreads();
  // zero-atomic flush: private partial slice per block
  for (int j = tid; j < 2048; j += 256)
    partial[(size_t)blockIdx.x * 2048 + j] = pools[j];
}

// ---------------- red: parallel partial reduction (128 blocks) ----------------
__global__ __launch_bounds__(256) void k_red(
    const float* __restrict__ partial, float* __restrict__ pooled) {
  __shared__ float red[256];
  int o = blockIdx.x * 16 + (threadIdx.x & 15);
  int sl = threadIdx.x >> 4;
  float s = 0.f;
  for (int g = sl; g < G3; g += 16) s += partial[(size_t)g * 2048 + o];
  red[threadIdx.x] = s;
  __syncthreads();
  if (threadIdx.x < 16) {
    float t = 0.f;
    #pragma unroll
    for (int k = 0; k < 16; k++) t += red[k * 16 + threadIdx.x];
    pooled[o] = t;
  }
}

// ---------------- fin: divide, linear, relu, softmax ----------------
__global__ void k_fin(const float* __restrict__ pooled, const float* __restrict__ cnt,
                      const float* __restrict__ wl, const float* __restrict__ bl,
                      float* __restrict__ out) {
  __shared__ float pr[128];
  __shared__ float lg[10];
  int b = blockIdx.x;
  int tid = threadIdx.x;
  pr[tid] = pooled[b * 128 + tid] / fmaxf(cnt[b], 1.0f);
  __syncthreads();
  if (tid < 10) {
    float acc = bl[tid];
    for (int j = 0; j < 128; j++) acc += pr[j] * wl[tid * 128 + j];
    lg[tid] = fmaxf(acc, 0.f);
  }
  __syncthreads();
  if (tid == 0) {
    float mx = lg[0];
    for (int k = 1; k < 10; k++) mx = fmaxf(mx, lg[k]);
    float se = 0.f;
    for (int k = 0; k < 10; k++) se += expf(lg[k] - mx);
    for (int k = 0; k < 10; k++) out[b * 10 + k] = expf(lg[k] - mx) / se;
  }
}

extern "C" void kernel_launch(void* const* d_in, const int* in_sizes, int n_in,
                              void* d_out, int out_size, void* d_ws, size_t ws_size,
                              hipStream_t stream) {
  const float* x  = (const float*)d_in[0];
  const float* w1 = (const float*)d_in[1];
  const float* w2 = (const float*)d_in[2];
  const float* w3 = (const float*)d_in[3];
  const float* wl = (const float*)d_in[4];
  const float* bl = (const float*)d_in[5];
  float* out = (float*)d_out;

  float* ws = (float*)d_ws;
  int* counter1 = (int*)(ws + 0);
  int* counter2 = (int*)(ws + 1);
  float* cnt = ws + 16;             // 16 floats
  float* pooled = ws + 32;          // 2048 floats (fully written by k_red)
  size_t off = 2080;                // 8B aligned
  unsigned long long* b1 = (unsigned long long*)(ws + off); off += NW1 * 2 + 2;
  unsigned long long* b2 = (unsigned long long*)(ws + off); off += NW2 * 2;
  int* wb1 = (int*)(ws + off); off += NW1;
  int* wb2 = (int*)(ws + off); off += NW2;
  int* idx1 = (int*)(ws + off); off += NP1;
  unsigned short* h1c = (unsigned short*)(ws + off); off += (size_t)CAP1 * 16;
  int* idx2 = (int*)(ws + off); off += NP2;
  int* list2 = (int*)(ws + off); off += CAP2;
  unsigned short* h2c = (unsigned short*)(ws + off); off += (size_t)CAP2 * 32;
  unsigned short* w2b = (unsigned short*)(ws + off); off += 128000;
  unsigned short* w3b = (unsigned short*)(ws + off); off += 110592;
  float* partial = ws + off; off += (size_t)G3 * 2048;

  hipMemsetAsync(d_ws, 0, 256, stream);  // counters + cnt

  k_tw2b<<<(256000 + 255) / 256, 256, 0, stream>>>(w2, w2b);
  k_tw3b<<<(221184 + 255) / 256, 256, 0, stream>>>(w3, w3b);
  k_ballot1<<<NP1 / 256, 256, 0, stream>>>(x, b1);
  k_ballot2<<<(NP2 + 255) / 256, 256, 0, stream>>>(b1, b2);
  k_scan<<<1, 1024, 0, stream>>>(b1, b2, wb1, wb2, counter1, counter2, cnt);
  k_conv1e<<<2048, 256, 0, stream>>>(x, w1, b1, wb1, h1c);
  k_fill1<<<NP1 / 256, 256, 0, stream>>>(b1, wb1, idx1);
  k_fill2<<<(NP2 + 255) / 256, 256, 0, stream>>>(b2, wb2, idx2, list2);
  k_conv2m<<<G2, 256, 0, stream>>>(h1c, w2b, idx1, list2, counter2, h2c);
  k_conv3m<<<G3, 256, 0, stream>>>(h2c, w3b, idx2, list2, counter2, partial);
  k_red<<<128, 256, 0, stream>>>(partial, pooled);
  k_fin<<<16, 128, 0, stream>>>(pooled, cnt, wl, bl, out);
}